// Round 13
// baseline (103.207 us; speedup 1.0000x reference)
//
#include <hip/hip_runtime.h>
#include <hip/hip_fp16.h>

// ROIAlign3D, separable interpolation; fp16 LDS staging, 2 channels/block,
// XCD-partitioned channel slices + spatially SORTED roi order (rank-sort by
// (batch, zmin, ymin) in a tiny pre-kernel) for L2 residency + DRAM order.
// x (B=2, C=96, D=40, H=96, W=96) f32, rois (K=256,7) f32 -> out (K,C,7,7,7) f32
// rois: [b, x1,y1,z1, x2,y2,z2]; x,y scaled 0.25, z scaled 0.5.

#define Bn 2
#define Cn 96
#define Dn 40
#define Hn 96
#define Wn 96
#define Kn 256
#define CELLS 343
#define NS 14                    // 7 pooled * SR 2 samples per axis
#define MAXZ 18                  // provable: z dense span <= 17
#define MAXY 32                  // provable: y dense span <= 31
#define MAXROWS (MAXZ * MAXY)    // 576
#define NT 384                   // threads per block (6 waves)
#define SLOTS 27                 // stage-1 row slots: 27*14 = 378 active threads
#define CPB 2                    // channels per block
#define NXCD 8
#define CGRP (Cn / CPB)          // 48 channel-groups
#define CG_PER_XCD (CGRP / NXCD) // 6
#define DHWc (Dn * Hn * Wn)      // 368640

typedef float float2u __attribute__((ext_vector_type(2), aligned(4)));

// ---- tiny rank-sort of rois by (batch, zmin, ymin); perm[pos] = roi id ----
__global__ __launch_bounds__(Kn) void roi_sort_kernel(
    const float* __restrict__ rois, int* __restrict__ perm)
{
    __shared__ int s_key[Kn];
    const int t = threadIdx.x;
    const float rb = rois[t*7+0];
    const float rz = rois[t*7+3]*0.5f;
    const float ry = rois[t*7+2]*0.25f;
    const int zq = (int)fminf(fmaxf(rz, 0.f), 63.f);          // 6 bits
    const int yq = ((int)fminf(fmaxf(ry, 0.f), 95.f)) >> 3;   // 4 bits
    s_key[t] = (((int)rb) << 16) | (zq << 8) | yq;
    __syncthreads();
    const int mykey = s_key[t];
    int pos = 0;
    for (int j = 0; j < Kn; ++j) {
        const int kj = s_key[j];
        pos += (kj < mykey) | ((kj == mykey) & (j < t));
    }
    perm[pos] = t;
}

__global__ __launch_bounds__(NT) void roialign3d_kernel(
    const float* __restrict__ x,
    const float* __restrict__ rois,
    const int*   __restrict__ perm,
    float* __restrict__ out)
{
    // ---- XCD-partitioned decode: xcd = bid % 8 owns channels [xcd*12, xcd*12+12) ----
    const int bid = blockIdx.x;
    const int xcd = bid & (NXCD - 1);
    const int j   = bid >> 3;            // 0 .. 256*6-1
    const int kj  = j & (Kn - 1);        // sorted-roi slot (fastest within slice)
    const int cgl = j >> 8;              // 0..5 local channel-group
    const int c0  = (xcd * CG_PER_XCD + cgl) * CPB;
    const int k   = perm[kj];            // original roi id (spatially sorted order)

    const int tid = threadIdx.x;

    __shared__ __half s_xi[MAXROWS * NS];  // 16128 B, x-interpolated samples (fp16)
    __shared__ int    s_rowoff[MAXROWS];   // 2304 B
    __shared__ int    s_lo[2][NS];         // axis 0=z, 1=y (absolute)
    __shared__ int    s_hi[2][NS];
    __shared__ float  s_wl[2][NS];
    __shared__ float  s_wh[2][NS];
    // total ~19.2 KB

    // ---- per-thread roi decode (uniform) ----
    const float rb  = rois[k*7+0];
    const float rx1 = rois[k*7+1]*0.25f, ry1 = rois[k*7+2]*0.25f, rz1 = rois[k*7+3]*0.5f;
    const float rx2 = rois[k*7+4]*0.25f, ry2 = rois[k*7+5]*0.25f, rz2 = rois[k*7+6]*0.5f;
    const int   bidx = (int)rb;
    const float binx = fmaxf(rx2-rx1, 1.0f) / 7.0f;
    const float biny = fmaxf(ry2-ry1, 1.0f) / 7.0f;
    const float binz = fmaxf(rz2-rz1, 1.0f) / 7.0f;

    // ---- per-lane x-sample registers (fixed xs = tid % 14 within slot) ----
    const int slot = tid / NS;
    const int xs   = tid - slot * NS;
    float wxl, wxh; int xlo;
    {
        const float cx = rx1 + ((float)(xs >> 1) + ((float)(xs & 1) + 0.5f) * 0.5f) * binx;
        const bool valid = (cx >= -1.0f) && (cx <= (float)Wn);
        const float cc = fminf(fmaxf(cx, 0.0f), (float)(Wn - 1));
        int lo = (int)floorf(cc);
        const float frac = cc - (float)lo;
        wxl = valid ? 1.0f - frac : 0.0f;
        wxh = valid ? frac : 0.0f;
        if (lo >= Wn - 1) { wxh = wxl; wxl = 0.0f; lo = Wn - 2; }  // frac==0 here
        xlo = lo;
    }

    // ---- z/y axis tables (28 threads) ----
    if (tid < 2 * NS) {
        const int axis = tid / NS;               // 0=z, 1=y
        const int i    = tid - axis * NS;
        const float start = (axis == 0) ? rz1 : ry1;
        const float bin   = (axis == 0) ? binz : biny;
        const float size  = (axis == 0) ? (float)Dn : (float)Hn;
        const float c0f = start + ((float)(i >> 1) + ((float)(i & 1) + 0.5f) * 0.5f) * bin;
        const bool valid = (c0f >= -1.0f) && (c0f <= size);
        const float cc = fminf(fmaxf(c0f, 0.0f), size - 1.0f);
        const int lo = (int)floorf(cc);
        const float frac = cc - (float)lo;
        s_lo[axis][i] = lo;
        s_hi[axis][i] = min(lo + 1, (int)size - 1);
        s_wl[axis][i] = valid ? 1.0f - frac : 0.0f;
        s_wh[axis][i] = valid ? frac : 0.0f;
    }
    __syncthreads();

    // dense box bounds (sample coords monotone)
    const int zmin = s_lo[0][0], ymin = s_lo[1][0];
    const int Zd = min(s_hi[0][NS-1] - zmin + 1, MAXZ);
    const int Yd = min(s_hi[1][NS-1] - ymin + 1, MAXY);
    const int nrows = Zd * Yd;

    for (int r = tid; r < nrows; r += NT) {
        const int zd = r / Yd;
        const int yd = r - zd * Yd;
        s_rowoff[r] = ((zmin + zd) * Hn + (ymin + yd)) * Wn;
    }
    __syncthreads();

    // ---- hoisted stage-2 per-cell registers (channel-invariant) ----
    const bool cellact = (tid < CELLS);
    int   zY[4], yN[4];
    float wzv[4], wyv[4];
    if (cellact) {
        const int pw = tid % 7;
        const int t7 = tid / 7;
        const int ph = t7 % 7;
        const int pd = t7 / 7;
        const int px2 = pw * 2;
        #pragma unroll
        for (int iz = 0; iz < 2; ++iz) {
            const int zi = pd * 2 + iz;
            zY[iz*2+0] = (s_lo[0][zi] - zmin) * (Yd * NS);
            zY[iz*2+1] = (s_hi[0][zi] - zmin) * (Yd * NS);
            wzv[iz*2+0] = s_wl[0][zi];
            wzv[iz*2+1] = s_wh[0][zi];
        }
        #pragma unroll
        for (int iy = 0; iy < 2; ++iy) {
            const int yi = ph * 2 + iy;
            yN[iy*2+0] = (s_lo[1][yi] - ymin) * NS + px2;
            yN[iy*2+1] = (s_hi[1][yi] - ymin) * NS + px2;
            wyv[iy*2+0] = s_wl[1][yi];
            wyv[iy*2+1] = s_wh[1][yi];
        }
    }

    const float* xb0 = x + ((long long)bidx * Cn + c0) * DHWc;
    const long long outbase = ((long long)k * Cn + c0) * CELLS;

    for (int cc = 0; cc < CPB; ++cc) {
        // ---- stage 1: x-interp over dense rows; 4-deep load batches ----
        const float* xb = xb0 + (long long)cc * DHWc;
        if (slot < SLOTS) {
            int row = slot;
            for (; row + 3 * SLOTS < nrows; row += 4 * SLOTS) {
                const int r0 = row, r1 = row + SLOTS, r2 = row + 2*SLOTS, r3 = row + 3*SLOTS;
                const int o0 = s_rowoff[r0], o1 = s_rowoff[r1],
                          o2 = s_rowoff[r2], o3 = s_rowoff[r3];
                const float2u f0 = *(const float2u*)(xb + o0 + xlo);
                const float2u f1 = *(const float2u*)(xb + o1 + xlo);
                const float2u f2 = *(const float2u*)(xb + o2 + xlo);
                const float2u f3 = *(const float2u*)(xb + o3 + xlo);
                s_xi[r0 * NS + xs] = __float2half(wxl * f0.x + wxh * f0.y);
                s_xi[r1 * NS + xs] = __float2half(wxl * f1.x + wxh * f1.y);
                s_xi[r2 * NS + xs] = __float2half(wxl * f2.x + wxh * f2.y);
                s_xi[r3 * NS + xs] = __float2half(wxl * f3.x + wxh * f3.y);
            }
            for (; row < nrows; row += SLOTS) {
                const float2u f = *(const float2u*)(xb + s_rowoff[row] + xlo);
                s_xi[row * NS + xs] = __float2half(wxl * f.x + wxh * f.y);
            }
        }
        __syncthreads();

        // ---- stage 2: y/z combine, one cell per thread ----
        if (cellact) {
            float acc = 0.0f;
            #pragma unroll
            for (int b = 0; b < 4; ++b) {
                float accb = 0.0f;
                #pragma unroll
                for (int a = 0; a < 4; ++a) {
                    const __half2 h = *(const __half2*)&s_xi[zY[a] + yN[b]];
                    accb += wzv[a] * (__low2float(h) + __high2float(h));
                }
                acc += wyv[b] * accb;
            }
            out[outbase + (long long)cc * CELLS + tid] = acc * 0.125f;
        }
        __syncthreads();   // s_xi reused by next channel
    }
}

extern "C" void kernel_launch(void* const* d_in, const int* in_sizes, int n_in,
                              void* d_out, int out_size, void* d_ws, size_t ws_size,
                              hipStream_t stream) {
    const float* x    = (const float*)d_in[0];
    const float* rois = (const float*)d_in[1];
    float* out        = (float*)d_out;
    int*   perm       = (int*)d_ws;      // 1 KB of scratch

    roi_sort_kernel<<<dim3(1), dim3(Kn), 0, stream>>>(rois, perm);
    // 1D grid: bid%8 -> XCD -> disjoint channel slice; sorted roi fastest.
    roialign3d_kernel<<<dim3(Kn * CGRP), dim3(NT), 0, stream>>>(x, rois, perm, out);
}

// Round 14
// 94.637 us; speedup vs baseline: 1.0906x; 1.0906x over previous
//
#include <hip/hip_runtime.h>
#include <hip/hip_fp16.h>

// ROIAlign3D, separable interpolation; fp16 LDS staging, 2 channels/block,
// XCD-partitioned channel swizzle: each XCD owns a disjoint 12-channel slice
// (kills 8x L3->L2 replication of the input across per-XCD L2s).
// x (B=2, C=96, D=40, H=96, W=96) f32, rois (K=256,7) f32 -> out (K,C,7,7,7) f32
// rois: [b, x1,y1,z1, x2,y2,z2]; x,y scaled 0.25, z scaled 0.5.
//
// Measured levers (MI355X): XCD channel partition -14%; occupancy/ILP/
// transaction-count/roi-sort all neutral-or-negative. Limiter: scattered
// 1-2-line HBM bursts at ~3.4 TB/s effective on ~326 MB compulsory fetch.

#define Bn 2
#define Cn 96
#define Dn 40
#define Hn 96
#define Wn 96
#define Kn 256
#define CELLS 343
#define NS 14                    // 7 pooled * SR 2 samples per axis
#define MAXZ 18                  // provable: z dense span <= 17
#define MAXY 32                  // provable: y dense span <= 31
#define MAXROWS (MAXZ * MAXY)    // 576
#define NT 384                   // threads per block (6 waves)
#define SLOTS 27                 // stage-1 row slots: 27*14 = 378 active threads
#define CPB 2                    // channels per block
#define NXCD 8
#define CGRP (Cn / CPB)          // 48 channel-groups
#define CG_PER_XCD (CGRP / NXCD) // 6
#define DHWc (Dn * Hn * Wn)      // 368640

typedef float float2u __attribute__((ext_vector_type(2), aligned(4)));

__global__ __launch_bounds__(NT) void roialign3d_kernel(
    const float* __restrict__ x,
    const float* __restrict__ rois,
    float* __restrict__ out)
{
    // ---- XCD-partitioned decode: xcd = bid % 8 owns channels [xcd*12, xcd*12+12) ----
    const int bid = blockIdx.x;
    const int xcd = bid & (NXCD - 1);
    const int j   = bid >> 3;            // 0 .. 256*6-1
    const int k   = j & (Kn - 1);        // roi fastest within an XCD's slice
    const int cgl = j >> 8;              // 0..5 local channel-group
    const int c0  = (xcd * CG_PER_XCD + cgl) * CPB;

    const int tid = threadIdx.x;

    __shared__ __half s_xi[MAXROWS * NS];  // 16128 B, x-interpolated samples (fp16)
    __shared__ int    s_rowoff[MAXROWS];   // 2304 B
    __shared__ int    s_lo[2][NS];         // axis 0=z, 1=y (absolute)
    __shared__ int    s_hi[2][NS];
    __shared__ float  s_wl[2][NS];
    __shared__ float  s_wh[2][NS];
    // total ~19.2 KB

    // ---- per-thread roi decode (uniform) ----
    const float rb  = rois[k*7+0];
    const float rx1 = rois[k*7+1]*0.25f, ry1 = rois[k*7+2]*0.25f, rz1 = rois[k*7+3]*0.5f;
    const float rx2 = rois[k*7+4]*0.25f, ry2 = rois[k*7+5]*0.25f, rz2 = rois[k*7+6]*0.5f;
    const int   bidx = (int)rb;
    const float binx = fmaxf(rx2-rx1, 1.0f) / 7.0f;
    const float biny = fmaxf(ry2-ry1, 1.0f) / 7.0f;
    const float binz = fmaxf(rz2-rz1, 1.0f) / 7.0f;

    // ---- per-lane x-sample registers (fixed xs = tid % 14 within slot) ----
    const int slot = tid / NS;
    const int xs   = tid - slot * NS;
    float wxl, wxh; int xlo;
    {
        const float cx = rx1 + ((float)(xs >> 1) + ((float)(xs & 1) + 0.5f) * 0.5f) * binx;
        const bool valid = (cx >= -1.0f) && (cx <= (float)Wn);
        const float cc = fminf(fmaxf(cx, 0.0f), (float)(Wn - 1));
        int lo = (int)floorf(cc);
        const float frac = cc - (float)lo;
        wxl = valid ? 1.0f - frac : 0.0f;
        wxh = valid ? frac : 0.0f;
        if (lo >= Wn - 1) { wxh = wxl; wxl = 0.0f; lo = Wn - 2; }  // frac==0 here
        xlo = lo;
    }

    // ---- z/y axis tables (28 threads) ----
    if (tid < 2 * NS) {
        const int axis = tid / NS;               // 0=z, 1=y
        const int i    = tid - axis * NS;
        const float start = (axis == 0) ? rz1 : ry1;
        const float bin   = (axis == 0) ? binz : biny;
        const float size  = (axis == 0) ? (float)Dn : (float)Hn;
        const float c0f = start + ((float)(i >> 1) + ((float)(i & 1) + 0.5f) * 0.5f) * bin;
        const bool valid = (c0f >= -1.0f) && (c0f <= size);
        const float cc = fminf(fmaxf(c0f, 0.0f), size - 1.0f);
        const int lo = (int)floorf(cc);
        const float frac = cc - (float)lo;
        s_lo[axis][i] = lo;
        s_hi[axis][i] = min(lo + 1, (int)size - 1);
        s_wl[axis][i] = valid ? 1.0f - frac : 0.0f;
        s_wh[axis][i] = valid ? frac : 0.0f;
    }
    __syncthreads();

    // dense box bounds (sample coords monotone)
    const int zmin = s_lo[0][0], ymin = s_lo[1][0];
    const int Zd = min(s_hi[0][NS-1] - zmin + 1, MAXZ);
    const int Yd = min(s_hi[1][NS-1] - ymin + 1, MAXY);
    const int nrows = Zd * Yd;

    for (int r = tid; r < nrows; r += NT) {
        const int zd = r / Yd;
        const int yd = r - zd * Yd;
        s_rowoff[r] = ((zmin + zd) * Hn + (ymin + yd)) * Wn;
    }
    __syncthreads();

    // ---- hoisted stage-2 per-cell registers (channel-invariant) ----
    const bool cellact = (tid < CELLS);
    int   zY[4], yN[4];
    float wzv[4], wyv[4];
    if (cellact) {
        const int pw = tid % 7;
        const int t7 = tid / 7;
        const int ph = t7 % 7;
        const int pd = t7 / 7;
        const int px2 = pw * 2;
        #pragma unroll
        for (int iz = 0; iz < 2; ++iz) {
            const int zi = pd * 2 + iz;
            zY[iz*2+0] = (s_lo[0][zi] - zmin) * (Yd * NS);
            zY[iz*2+1] = (s_hi[0][zi] - zmin) * (Yd * NS);
            wzv[iz*2+0] = s_wl[0][zi];
            wzv[iz*2+1] = s_wh[0][zi];
        }
        #pragma unroll
        for (int iy = 0; iy < 2; ++iy) {
            const int yi = ph * 2 + iy;
            yN[iy*2+0] = (s_lo[1][yi] - ymin) * NS + px2;
            yN[iy*2+1] = (s_hi[1][yi] - ymin) * NS + px2;
            wyv[iy*2+0] = s_wl[1][yi];
            wyv[iy*2+1] = s_wh[1][yi];
        }
    }

    const float* xb0 = x + ((long long)bidx * Cn + c0) * DHWc;
    const long long outbase = ((long long)k * Cn + c0) * CELLS;

    for (int cc = 0; cc < CPB; ++cc) {
        // ---- stage 1: x-interp over dense rows; 4-deep load batches ----
        const float* xb = xb0 + (long long)cc * DHWc;
        if (slot < SLOTS) {
            int row = slot;
            for (; row + 3 * SLOTS < nrows; row += 4 * SLOTS) {
                const int r0 = row, r1 = row + SLOTS, r2 = row + 2*SLOTS, r3 = row + 3*SLOTS;
                const int o0 = s_rowoff[r0], o1 = s_rowoff[r1],
                          o2 = s_rowoff[r2], o3 = s_rowoff[r3];
                const float2u f0 = *(const float2u*)(xb + o0 + xlo);
                const float2u f1 = *(const float2u*)(xb + o1 + xlo);
                const float2u f2 = *(const float2u*)(xb + o2 + xlo);
                const float2u f3 = *(const float2u*)(xb + o3 + xlo);
                s_xi[r0 * NS + xs] = __float2half(wxl * f0.x + wxh * f0.y);
                s_xi[r1 * NS + xs] = __float2half(wxl * f1.x + wxh * f1.y);
                s_xi[r2 * NS + xs] = __float2half(wxl * f2.x + wxh * f2.y);
                s_xi[r3 * NS + xs] = __float2half(wxl * f3.x + wxh * f3.y);
            }
            for (; row < nrows; row += SLOTS) {
                const float2u f = *(const float2u*)(xb + s_rowoff[row] + xlo);
                s_xi[row * NS + xs] = __float2half(wxl * f.x + wxh * f.y);
            }
        }
        __syncthreads();

        // ---- stage 2: y/z combine, one cell per thread ----
        if (cellact) {
            float acc = 0.0f;
            #pragma unroll
            for (int b = 0; b < 4; ++b) {
                float accb = 0.0f;
                #pragma unroll
                for (int a = 0; a < 4; ++a) {
                    const __half2 h = *(const __half2*)&s_xi[zY[a] + yN[b]];
                    accb += wzv[a] * (__low2float(h) + __high2float(h));
                }
                acc += wyv[b] * accb;
            }
            out[outbase + (long long)cc * CELLS + tid] = acc * 0.125f;
        }
        __syncthreads();   // s_xi reused by next channel
    }
}

extern "C" void kernel_launch(void* const* d_in, const int* in_sizes, int n_in,
                              void* d_out, int out_size, void* d_ws, size_t ws_size,
                              hipStream_t stream) {
    const float* x    = (const float*)d_in[0];
    const float* rois = (const float*)d_in[1];
    float* out        = (float*)d_out;

    // 1D grid: bid%8 -> XCD -> disjoint channel slice; k fastest within slice.
    roialign3d_kernel<<<dim3(Kn * CGRP), dim3(NT), 0, stream>>>(x, rois, out);
}